// Round 1
// baseline (3489.601 us; speedup 1.0000x reference)
//
#include <hip/hip_runtime.h>

// Problem constants
#define Bn 4
#define Tn 2048
#define Cn 1024
#define Hn 16
#define HDn 64
#define Mn (Bn * Tn)  // 8192 tokens

// ---------------------------------------------------------------------------
// Tiled fp32 GEMM with bias: Out[M,N] = A[M,K] @ W[K,N] + bias[N]
// BM=BN=64, BK=16, 256 threads, 4x4 microtile per thread.
// ---------------------------------------------------------------------------
__global__ __launch_bounds__(256) void gemm_bias_kernel(
    const float* __restrict__ A, const float* __restrict__ W,
    const float* __restrict__ bias, float* __restrict__ Out,
    int M, int N, int K)
{
    constexpr int BK = 16;
    __shared__ float As[64][17];   // +1 pad breaks power-of-2 bank stride
    __shared__ float Bs[16][64];

    const int tid = threadIdx.x;
    const int tx = tid & 15;       // 16 col-groups
    const int ty = tid >> 4;       // 16 row-groups
    const int brow = blockIdx.y * 64;
    const int bcol = blockIdx.x * 64;

    float acc[4][4] = {};

    for (int k0 = 0; k0 < K; k0 += BK) {
        // Load A tile 64x16 (each thread: 4 consecutive k of one row, float4)
        {
            const int e  = tid * 4;
            const int r  = e >> 4;
            const int kk = e & 15;
            const float4 av =
                *reinterpret_cast<const float4*>(&A[(size_t)(brow + r) * K + k0 + kk]);
            As[r][kk + 0] = av.x; As[r][kk + 1] = av.y;
            As[r][kk + 2] = av.z; As[r][kk + 3] = av.w;
        }
        // Load B tile 16x64 (each thread: 4 consecutive cols of one k-row)
        {
            const int e  = tid * 4;
            const int r  = e >> 6;
            const int cc = e & 63;
            *reinterpret_cast<float4*>(&Bs[r][cc]) =
                *reinterpret_cast<const float4*>(&W[(size_t)(k0 + r) * N + bcol + cc]);
        }
        __syncthreads();

        #pragma unroll
        for (int kk = 0; kk < BK; ++kk) {
            float a[4], b[4];
            #pragma unroll
            for (int i = 0; i < 4; ++i) a[i] = As[ty * 4 + i][kk];
            #pragma unroll
            for (int j = 0; j < 4; ++j) b[j] = Bs[kk][tx * 4 + j];
            #pragma unroll
            for (int i = 0; i < 4; ++i)
                #pragma unroll
                for (int j = 0; j < 4; ++j)
                    acc[i][j] = fmaf(a[i], b[j], acc[i][j]);
        }
        __syncthreads();
    }

    #pragma unroll
    for (int i = 0; i < 4; ++i) {
        const int r = brow + ty * 4 + i;
        #pragma unroll
        for (int j = 0; j < 4; ++j) {
            const int c = bcol + tx * 4 + j;
            Out[(size_t)r * N + c] = acc[i][j] + bias[c];
        }
    }
}

// ---------------------------------------------------------------------------
// Flash-style causal attention, fp32.
// qkv layout: [B*T, 3*C] rows; q at col h*64, k at C + h*64, v at 2C + h*64.
// One block = one (b,h) and one 64-row Q tile. 256 threads:
//   row r = tid>>2 (0..63), col-group cg = tid&3 (16 cols each).
// Online softmax; P staged via LDS for the PV step.
// y layout: [B*T, C] with head h at cols h*64..h*64+63.
// ---------------------------------------------------------------------------
__global__ __launch_bounds__(256) void attn_kernel(
    const float* __restrict__ qkv, float* __restrict__ y)
{
    __shared__ float Qs[64][68];
    __shared__ float Ks[64][68];
    __shared__ float Vs[64][68];
    __shared__ float Ps[64][68];

    const int tid = threadIdx.x;
    const int qt  = blockIdx.x;          // Q tile index (0..31)
    const int bh  = blockIdx.y;          // b*H + h
    const int b   = bh >> 4;
    const int h   = bh & 15;

    const size_t base = ((size_t)b * Tn) * (3 * Cn) + (size_t)h * HDn;
    const float* Qg = qkv + base;
    const float* Kg = qkv + base + Cn;
    const float* Vg = qkv + base + 2 * Cn;

    // Load Q tile 64x64
    for (int cc = 0; cc < 4; ++cc) {
        const int e = (tid + cc * 256) * 4;
        const int r = e >> 6;
        const int d = e & 63;
        const float4 v =
            *reinterpret_cast<const float4*>(&Qg[(size_t)(qt * 64 + r) * (3 * Cn) + d]);
        Qs[r][d + 0] = v.x; Qs[r][d + 1] = v.y;
        Qs[r][d + 2] = v.z; Qs[r][d + 3] = v.w;
    }

    const int r  = tid >> 2;
    const int cg = tid & 3;
    const int qglob = qt * 64 + r;
    const float scale = 0.125f;  // 1/sqrt(64)

    float m = -INFINITY, l = 0.f;
    float O[16];
    #pragma unroll
    for (int j = 0; j < 16; ++j) O[j] = 0.f;

    for (int kt = 0; kt <= qt; ++kt) {
        __syncthreads();   // previous iteration's Ks/Vs/Ps reads complete
        // Load K and V tiles (64x64 each)
        for (int cc = 0; cc < 4; ++cc) {
            const int e  = (tid + cc * 256) * 4;
            const int rr = e >> 6;
            const int d  = e & 63;
            const size_t go = (size_t)(kt * 64 + rr) * (3 * Cn) + d;
            const float4 kv4 = *reinterpret_cast<const float4*>(&Kg[go]);
            Ks[rr][d + 0] = kv4.x; Ks[rr][d + 1] = kv4.y;
            Ks[rr][d + 2] = kv4.z; Ks[rr][d + 3] = kv4.w;
            const float4 vv4 = *reinterpret_cast<const float4*>(&Vg[go]);
            Vs[rr][d + 0] = vv4.x; Vs[rr][d + 1] = vv4.y;
            Vs[rr][d + 2] = vv4.z; Vs[rr][d + 3] = vv4.w;
        }
        __syncthreads();

        // S = Q K^T for this thread's 16 columns
        float s[16];
        #pragma unroll
        for (int j = 0; j < 16; ++j) s[j] = 0.f;
        #pragma unroll 8
        for (int d = 0; d < 64; ++d) {
            const float qd = Qs[r][d];
            #pragma unroll
            for (int j = 0; j < 16; ++j)
                s[j] = fmaf(qd, Ks[cg * 16 + j][d], s[j]);
        }
        // scale + causal mask
        #pragma unroll
        for (int j = 0; j < 16; ++j) {
            const int kglob = kt * 64 + cg * 16 + j;
            s[j] = (kglob <= qglob) ? s[j] * scale : -INFINITY;
        }

        // row max (16 local + 4-lane shuffle)
        float mt = s[0];
        #pragma unroll
        for (int j = 1; j < 16; ++j) mt = fmaxf(mt, s[j]);
        mt = fmaxf(mt, __shfl_xor(mt, 1));
        mt = fmaxf(mt, __shfl_xor(mt, 2));
        const float m_new = fmaxf(m, mt);
        const float alpha = __expf(m - m_new);

        float lt = 0.f;
        #pragma unroll
        for (int j = 0; j < 16; ++j) {
            const float p = __expf(s[j] - m_new);
            Ps[r][cg * 16 + j] = p;
            lt += p;
        }
        lt += __shfl_xor(lt, 1);
        lt += __shfl_xor(lt, 2);
        l = l * alpha + lt;
        m = m_new;
        __syncthreads();   // Ps visible to all threads of the row

        // O = O*alpha + P @ V   (this thread: row r, d-cols cg*16..+15)
        #pragma unroll
        for (int j = 0; j < 16; ++j) O[j] *= alpha;
        #pragma unroll 8
        for (int k = 0; k < 64; ++k) {
            const float pk = Ps[r][k];
            #pragma unroll
            for (int j = 0; j < 16; ++j)
                O[j] = fmaf(pk, Vs[k][cg * 16 + j], O[j]);
        }
    }

    const float inv_l = 1.f / l;
    float* yrow = y + ((size_t)b * Tn + qglob) * Cn + (size_t)h * HDn;
    #pragma unroll
    for (int j = 0; j < 16; ++j)
        yrow[cg * 16 + j] = O[j] * inv_l;
}

// ---------------------------------------------------------------------------
extern "C" void kernel_launch(void* const* d_in, const int* in_sizes, int n_in,
                              void* d_out, int out_size, void* d_ws, size_t ws_size,
                              hipStream_t stream)
{
    const float* x      = (const float*)d_in[0];
    const float* W_attn = (const float*)d_in[1];
    const float* b_attn = (const float*)d_in[2];
    const float* W_proj = (const float*)d_in[3];
    const float* b_proj = (const float*)d_in[4];
    float* out = (float*)d_out;

    // Workspace: qkv [8192,3072] then y [8192,1024]  => 128 MiB total.
    float* qkv = (float*)d_ws;
    float* y   = qkv + (size_t)Mn * 3 * Cn;

    dim3 blk(256);

    // 1) qkv = x @ W_attn + b_attn   [8192,1024]x[1024,3072]
    gemm_bias_kernel<<<dim3(3 * Cn / 64, Mn / 64), blk, 0, stream>>>(
        x, W_attn, b_attn, qkv, Mn, 3 * Cn, Cn);

    // 2) causal flash attention  -> y [8192,1024]
    attn_kernel<<<dim3(Tn / 64, Bn * Hn), blk, 0, stream>>>(qkv, y);

    // 3) out = y @ W_proj + b_proj  [8192,1024]x[1024,1024]
    gemm_bias_kernel<<<dim3(Cn / 64, Mn / 64), blk, 0, stream>>>(
        y, W_proj, b_proj, out, Mn, Cn, Cn);
}

// Round 2
// 1517.585 us; speedup vs baseline: 2.2994x; 2.2994x over previous
//
#include <hip/hip_runtime.h>
#include <math.h>

// Problem constants
#define Bn 4
#define Tn 2048
#define Cn 1024
#define Hn 16
#define HDn 64
#define Mn (Bn * Tn)  // 8192 tokens

typedef unsigned short u16;
typedef unsigned int u32;
typedef __attribute__((ext_vector_type(8))) short bf16x8;  // 8 bf16 = 4 VGPRs
typedef __attribute__((ext_vector_type(4))) float f32x4;   // MFMA accumulator

__device__ __forceinline__ float b2f(u16 u) {
    return __uint_as_float(((u32)u) << 16);
}
__device__ __forceinline__ u16 f2b(float f) {
    u32 u = __float_as_uint(f);
    return (u16)((u + 0x7FFFu + ((u >> 16) & 1u)) >> 16);  // RNE
}

// ---------------------------------------------------------------------------
// fp32 -> bf16 elementwise convert (vectorized: float4 in, 4x bf16 out)
// ---------------------------------------------------------------------------
__global__ __launch_bounds__(256) void cvt_f32_bf16_kernel(
    const float4* __restrict__ in, ushort4* __restrict__ out, int n4)
{
    int i = blockIdx.x * 256 + threadIdx.x;
    if (i < n4) {
        float4 v = in[i];
        ushort4 o;
        o.x = f2b(v.x); o.y = f2b(v.y); o.z = f2b(v.z); o.w = f2b(v.w);
        out[i] = o;
    }
}

// ---------------------------------------------------------------------------
// Transpose + convert: in [R,Cc] fp32 -> out [Cc,R] bf16. 32x32 LDS tiles.
// ---------------------------------------------------------------------------
__global__ __launch_bounds__(256) void transpose_cvt_kernel(
    const float* __restrict__ in, u16* __restrict__ out, int R, int Cc)
{
    __shared__ u16 t[32][33];
    const int c0 = blockIdx.x * 32, r0 = blockIdx.y * 32;
    const int tx = threadIdx.x & 31, ty = threadIdx.x >> 5;  // 32 x 8
    #pragma unroll
    for (int i = 0; i < 32; i += 8)
        t[ty + i][tx] = f2b(in[(size_t)(r0 + ty + i) * Cc + c0 + tx]);
    __syncthreads();
    #pragma unroll
    for (int i = 0; i < 32; i += 8)
        out[(size_t)(c0 + ty + i) * R + r0 + tx] = t[tx][ty + i];
}

// ---------------------------------------------------------------------------
// bf16 MFMA GEMM: Out[M,N] = A[M,K] @ BT[N,K]^T + bias[N]
// 128x128 tile, BK=32, 256 threads (4 waves, 2x2), each wave 64x64 (4x4 frags
// of 16x16x32). LDS rows padded to 40 ushorts (80B) -> <=2-way bank conflicts.
// ---------------------------------------------------------------------------
template <bool OUT_BF16>
__global__ __launch_bounds__(256) void gemm_bf16_kernel(
    const u16* __restrict__ A,   // [M,K] bf16
    const u16* __restrict__ BT,  // [N,K] bf16 (pre-transposed weights)
    const float* __restrict__ bias,
    u16* __restrict__ outb, float* __restrict__ outf,
    int N, int K)
{
    __shared__ uint4 Al[128 * 5];  // 128 rows x 5 uint4 (4 used + pad)
    __shared__ uint4 Bl[128 * 5];

    const int tid = threadIdx.x;
    const int brow = blockIdx.y * 128;
    const int bcol = blockIdx.x * 128;
    const int w  = tid >> 6;
    const int wr = w >> 1, wc = w & 1;
    const int l  = tid & 63;
    const int lr = l & 15;          // fragment row/col
    const int lk = (l >> 4) << 3;   // k offset: 0,8,16,24 (8 contiguous bf16)

    f32x4 zero = {0.f, 0.f, 0.f, 0.f};
    f32x4 acc[4][4];
    #pragma unroll
    for (int m = 0; m < 4; ++m)
        #pragma unroll
        for (int n = 0; n < 4; ++n) acc[m][n] = zero;

    for (int k0 = 0; k0 < K; k0 += 32) {
        __syncthreads();  // protect prior iteration's fragment reads
        #pragma unroll
        for (int i = 0; i < 2; ++i) {
            const int c   = tid + (i << 8);   // 0..511
            const int row = c >> 2;           // 0..127
            const int kc  = c & 3;            // 16B chunk within row
            Al[row * 5 + kc] = *(const uint4*)&A [(size_t)(brow + row) * K + k0 + (kc << 3)];
            Bl[row * 5 + kc] = *(const uint4*)&BT[(size_t)(bcol + row) * K + k0 + (kc << 3)];
        }
        __syncthreads();

        const u16* Als = (const u16*)Al;
        const u16* Bls = (const u16*)Bl;
        bf16x8 a[4], b[4];
        #pragma unroll
        for (int m = 0; m < 4; ++m)
            a[m] = *(const bf16x8*)&Als[(wr * 64 + m * 16 + lr) * 40 + lk];
        #pragma unroll
        for (int n = 0; n < 4; ++n)
            b[n] = *(const bf16x8*)&Bls[(wc * 64 + n * 16 + lr) * 40 + lk];

        #pragma unroll
        for (int m = 0; m < 4; ++m)
            #pragma unroll
            for (int n = 0; n < 4; ++n)
                acc[m][n] = __builtin_amdgcn_mfma_f32_16x16x32_bf16(
                    a[m], b[n], acc[m][n], 0, 0, 0);
    }

    // Epilogue. C/D layout: col = lane&15, row = (lane>>4)*4 + reg.
    const int orow0 = brow + wr * 64 + ((l >> 4) << 2);
    const int ocol0 = bcol + wc * 64 + lr;
    #pragma unroll
    for (int n = 0; n < 4; ++n) {
        const int col = ocol0 + n * 16;
        const float bv = bias[col];
        #pragma unroll
        for (int m = 0; m < 4; ++m) {
            #pragma unroll
            for (int r = 0; r < 4; ++r) {
                const int row = orow0 + m * 16 + r;
                const float v = acc[m][n][r] + bv;
                if (OUT_BF16) outb[(size_t)row * N + col] = f2b(v);
                else          outf[(size_t)row * N + col] = v;
            }
        }
    }
}

// ---------------------------------------------------------------------------
// Flash-style causal attention, fp32 compute, bf16 qkv in / bf16 y out.
// Block = 256 threads (4 waves) = one 64-row Q tile of one (b,h).
// Thread (ty=tid>>4, tx=tid&15): owns S/O block rows {4ty+i} x cols {4tx+j}.
// LDS stride 65 floats: all hot read patterns <=2-way bank aliasing (free).
// P rows are wave-local (ty group = one wave) -> no barrier around P.
// ---------------------------------------------------------------------------
__global__ __launch_bounds__(256) void attn_kernel2(
    const u16* __restrict__ qkvb, u16* __restrict__ yb)
{
    __shared__ float Qs[64 * 65];
    __shared__ float Ks[64 * 65];
    __shared__ float Vs[64 * 65];
    __shared__ float Ps[64 * 65];

    const int tid = threadIdx.x;
    const int qt  = blockIdx.x;
    const int bh  = blockIdx.y;
    const int b   = bh >> 4, h = bh & 15;

    const size_t base = ((size_t)b * Tn) * (3 * Cn) + (size_t)h * HDn;
    const u16* Qg = qkvb + base;
    const u16* Kg = qkvb + base + Cn;
    const u16* Vg = qkvb + base + 2 * Cn;

    // Load Q tile 64x64 (bf16 -> f32 LDS)
    #pragma unroll
    for (int i = 0; i < 4; ++i) {
        const int c = tid + (i << 8);
        const int row = c >> 4, d4 = (c & 15) << 2;
        ushort4 v = *(const ushort4*)&Qg[(size_t)(qt * 64 + row) * (3 * Cn) + d4];
        float* q = &Qs[row * 65 + d4];
        q[0] = b2f(v.x); q[1] = b2f(v.y); q[2] = b2f(v.z); q[3] = b2f(v.w);
    }

    const int ty = tid >> 4, tx = tid & 15;
    const int r0 = ty << 2;   // q rows r0..r0+3 (within tile)
    const int c0 = tx << 2;   // k cols / d cols c0..c0+3

    float m[4], lsum[4], O[4][4];
    #pragma unroll
    for (int i = 0; i < 4; ++i) {
        m[i] = -INFINITY; lsum[i] = 0.f;
        #pragma unroll
        for (int j = 0; j < 4; ++j) O[i][j] = 0.f;
    }

    for (int kt = 0; kt <= qt; ++kt) {
        __syncthreads();  // prior tile's Ks/Vs reads complete
        #pragma unroll
        for (int i = 0; i < 4; ++i) {
            const int c = tid + (i << 8);
            const int row = c >> 4, d4 = (c & 15) << 2;
            const size_t go = (size_t)(kt * 64 + row) * (3 * Cn) + d4;
            ushort4 kv = *(const ushort4*)&Kg[go];
            float* kd = &Ks[row * 65 + d4];
            kd[0] = b2f(kv.x); kd[1] = b2f(kv.y); kd[2] = b2f(kv.z); kd[3] = b2f(kv.w);
            ushort4 vv = *(const ushort4*)&Vg[go];
            float* vd = &Vs[row * 65 + d4];
            vd[0] = b2f(vv.x); vd[1] = b2f(vv.y); vd[2] = b2f(vv.z); vd[3] = b2f(vv.w);
        }
        __syncthreads();

        // S = Q K^T  (4x4 register block; 8 LDS reads per 16 FMA)
        float s[4][4];
        #pragma unroll
        for (int i = 0; i < 4; ++i)
            #pragma unroll
            for (int j = 0; j < 4; ++j) s[i][j] = 0.f;
        #pragma unroll 4
        for (int kk = 0; kk < 64; ++kk) {
            float av[4], bv[4];
            #pragma unroll
            for (int i = 0; i < 4; ++i) av[i] = Qs[(r0 + i) * 65 + kk];
            #pragma unroll
            for (int j = 0; j < 4; ++j) bv[j] = Ks[(c0 + j) * 65 + kk];
            #pragma unroll
            for (int i = 0; i < 4; ++i)
                #pragma unroll
                for (int j = 0; j < 4; ++j)
                    s[i][j] = fmaf(av[i], bv[j], s[i][j]);
        }

        // scale + causal mask
        const int kb = kt * 64 + c0;
        const int qb = qt * 64 + r0;
        #pragma unroll
        for (int i = 0; i < 4; ++i)
            #pragma unroll
            for (int j = 0; j < 4; ++j)
                s[i][j] = (kb + j <= qb + i) ? s[i][j] * 0.125f : -INFINITY;

        // online softmax per row (reduce across 16 tx lanes)
        #pragma unroll
        for (int i = 0; i < 4; ++i) {
            float mt = fmaxf(fmaxf(s[i][0], s[i][1]), fmaxf(s[i][2], s[i][3]));
            mt = fmaxf(mt, __shfl_xor(mt, 1));
            mt = fmaxf(mt, __shfl_xor(mt, 2));
            mt = fmaxf(mt, __shfl_xor(mt, 4));
            mt = fmaxf(mt, __shfl_xor(mt, 8));
            const float mn = fmaxf(m[i], mt);
            const float alpha = __expf(m[i] - mn);
            m[i] = mn;
            float lt = 0.f;
            #pragma unroll
            for (int j = 0; j < 4; ++j) {
                const float p = __expf(s[i][j] - mn);
                Ps[(r0 + i) * 65 + c0 + j] = p;
                lt += p;
            }
            lt += __shfl_xor(lt, 1);
            lt += __shfl_xor(lt, 2);
            lt += __shfl_xor(lt, 4);
            lt += __shfl_xor(lt, 8);
            lsum[i] = lsum[i] * alpha + lt;
            #pragma unroll
            for (int j = 0; j < 4; ++j) O[i][j] *= alpha;
        }

        // O += P @ V  (P rows wave-local; per-wave DS ordering suffices)
        #pragma unroll 4
        for (int k = 0; k < 64; ++k) {
            float pv[4], vv[4];
            #pragma unroll
            for (int i = 0; i < 4; ++i) pv[i] = Ps[(r0 + i) * 65 + k];
            #pragma unroll
            for (int j = 0; j < 4; ++j) vv[j] = Vs[k * 65 + c0 + j];
            #pragma unroll
            for (int i = 0; i < 4; ++i)
                #pragma unroll
                for (int j = 0; j < 4; ++j)
                    O[i][j] = fmaf(pv[i], vv[j], O[i][j]);
        }
    }

    #pragma unroll
    for (int i = 0; i < 4; ++i) {
        const float inv = 1.f / lsum[i];
        const size_t ro = ((size_t)b * Tn + qt * 64 + r0 + i) * Cn + h * HDn + c0;
        #pragma unroll
        for (int j = 0; j < 4; ++j)
            yb[ro + j] = f2b(O[i][j] * inv);
    }
}

// ---------------------------------------------------------------------------
extern "C" void kernel_launch(void* const* d_in, const int* in_sizes, int n_in,
                              void* d_out, int out_size, void* d_ws, size_t ws_size,
                              hipStream_t stream)
{
    const float* x      = (const float*)d_in[0];
    const float* W_attn = (const float*)d_in[1];
    const float* b_attn = (const float*)d_in[2];
    const float* W_proj = (const float*)d_in[3];
    const float* b_proj = (const float*)d_in[4];
    float* out = (float*)d_out;

    // Workspace (bf16 elements): xb | WaT | WpT | qkvb | yb   (~92 MB)
    u16* xb   = (u16*)d_ws;
    u16* WaT  = xb   + (size_t)Mn * Cn;
    u16* WpT  = WaT  + (size_t)3 * Cn * Cn;
    u16* qkvb = WpT  + (size_t)Cn * Cn;
    u16* yb   = qkvb + (size_t)Mn * 3 * Cn;

    // 1) convert x to bf16
    cvt_f32_bf16_kernel<<<(Mn * Cn / 4 + 255) / 256, 256, 0, stream>>>(
        (const float4*)x, (ushort4*)xb, Mn * Cn / 4);

    // 2) transpose+convert weights to [N,K] bf16
    transpose_cvt_kernel<<<dim3(3 * Cn / 32, Cn / 32), 256, 0, stream>>>(
        W_attn, WaT, Cn, 3 * Cn);
    transpose_cvt_kernel<<<dim3(Cn / 32, Cn / 32), 256, 0, stream>>>(
        W_proj, WpT, Cn, Cn);

    // 3) qkv = x @ W_attn + b_attn   (bf16 out)
    gemm_bf16_kernel<true><<<dim3(3 * Cn / 128, Mn / 128), 256, 0, stream>>>(
        xb, WaT, b_attn, qkvb, nullptr, 3 * Cn, Cn);

    // 4) causal attention -> yb (bf16)
    attn_kernel2<<<dim3(Tn / 64, Bn * Hn), 256, 0, stream>>>(qkvb, yb);

    // 5) out = y @ W_proj + b_proj   (f32 out)
    gemm_bf16_kernel<false><<<dim3(Cn / 128, Mn / 128), 256, 0, stream>>>(
        yb, WpT, b_proj, nullptr, out, Cn, Cn);
}

// Round 3
// 377.411 us; speedup vs baseline: 9.2462x; 4.0210x over previous
//
#include <hip/hip_runtime.h>
#include <math.h>

// Problem constants
#define Bn 4
#define Tn 2048
#define Cn 1024
#define Hn 16
#define HDn 64
#define Mn (Bn * Tn)  // 8192 tokens

typedef unsigned short u16;
typedef unsigned int u32;
typedef __attribute__((ext_vector_type(8))) short bf16x8;        // 8 bf16 = 4 VGPRs
typedef __attribute__((ext_vector_type(8))) unsigned short us8;  // 16B chunk
typedef __attribute__((ext_vector_type(4))) float f32x4;         // MFMA accumulator

__device__ __forceinline__ float b2f(u16 u) {
    return __uint_as_float(((u32)u) << 16);
}
__device__ __forceinline__ u16 f2b(float f) {
    u32 u = __float_as_uint(f);
    return (u16)((u + 0x7FFFu + ((u >> 16) & 1u)) >> 16);  // RNE
}

// ---------------------------------------------------------------------------
// fp32 -> bf16 elementwise convert
// ---------------------------------------------------------------------------
__global__ __launch_bounds__(256) void cvt_f32_bf16_kernel(
    const float4* __restrict__ in, ushort4* __restrict__ out, int n4)
{
    int i = blockIdx.x * 256 + threadIdx.x;
    if (i < n4) {
        float4 v = in[i];
        ushort4 o;
        o.x = f2b(v.x); o.y = f2b(v.y); o.z = f2b(v.z); o.w = f2b(v.w);
        out[i] = o;
    }
}

// ---------------------------------------------------------------------------
// Transpose + convert: in [R,Cc] fp32 -> out [Cc,R] bf16. 32x32 LDS tiles.
// ---------------------------------------------------------------------------
__global__ __launch_bounds__(256) void transpose_cvt_kernel(
    const float* __restrict__ in, u16* __restrict__ out, int R, int Cc)
{
    __shared__ u16 t[32][33];
    const int c0 = blockIdx.x * 32, r0 = blockIdx.y * 32;
    const int tx = threadIdx.x & 31, ty = threadIdx.x >> 5;  // 32 x 8
    #pragma unroll
    for (int i = 0; i < 32; i += 8)
        t[ty + i][tx] = f2b(in[(size_t)(r0 + ty + i) * Cc + c0 + tx]);
    __syncthreads();
    #pragma unroll
    for (int i = 0; i < 32; i += 8)
        out[(size_t)(c0 + ty + i) * R + r0 + tx] = t[tx][ty + i];
}

// ---------------------------------------------------------------------------
// V transpose: qkv V-section [B][T][C] bf16 -> vT [B][C][T] bf16.
// (row of vT = (b*16+h)*64 + d, i.e. per-head d-major.)
// ---------------------------------------------------------------------------
__global__ __launch_bounds__(256) void transpose_v_kernel(
    const u16* __restrict__ qkvb, u16* __restrict__ vT)
{
    __shared__ u16 t[32][33];
    const int c0 = blockIdx.x * 32, t0 = blockIdx.y * 32, b = blockIdx.z;
    const int tx = threadIdx.x & 31, ty = threadIdx.x >> 5;  // 32 x 8
    #pragma unroll
    for (int i = 0; i < 32; i += 8)
        t[ty + i][tx] =
            qkvb[(size_t)(b * Tn + t0 + ty + i) * (3 * Cn) + 2 * Cn + c0 + tx];
    __syncthreads();
    #pragma unroll
    for (int i = 0; i < 32; i += 8)
        vT[(size_t)(b * Cn + c0 + ty + i) * Tn + t0 + tx] = t[tx][ty + i];
}

// ---------------------------------------------------------------------------
// bf16 MFMA GEMM: Out[M,N] = A[M,K] @ BT[N,K]^T + bias[N]  (unchanged, verified)
// ---------------------------------------------------------------------------
template <bool OUT_BF16>
__global__ __launch_bounds__(256) void gemm_bf16_kernel(
    const u16* __restrict__ A, const u16* __restrict__ BT,
    const float* __restrict__ bias,
    u16* __restrict__ outb, float* __restrict__ outf,
    int N, int K)
{
    __shared__ uint4 Al[128 * 5];
    __shared__ uint4 Bl[128 * 5];

    const int tid = threadIdx.x;
    const int brow = blockIdx.y * 128;
    const int bcol = blockIdx.x * 128;
    const int w  = tid >> 6;
    const int wr = w >> 1, wc = w & 1;
    const int l  = tid & 63;
    const int lr = l & 15;
    const int lk = (l >> 4) << 3;

    f32x4 zero = {0.f, 0.f, 0.f, 0.f};
    f32x4 acc[4][4];
    #pragma unroll
    for (int m = 0; m < 4; ++m)
        #pragma unroll
        for (int n = 0; n < 4; ++n) acc[m][n] = zero;

    for (int k0 = 0; k0 < K; k0 += 32) {
        __syncthreads();
        #pragma unroll
        for (int i = 0; i < 2; ++i) {
            const int c   = tid + (i << 8);
            const int row = c >> 2;
            const int kc  = c & 3;
            Al[row * 5 + kc] = *(const uint4*)&A [(size_t)(brow + row) * K + k0 + (kc << 3)];
            Bl[row * 5 + kc] = *(const uint4*)&BT[(size_t)(bcol + row) * K + k0 + (kc << 3)];
        }
        __syncthreads();

        const u16* Als = (const u16*)Al;
        const u16* Bls = (const u16*)Bl;
        bf16x8 a[4], b[4];
        #pragma unroll
        for (int m = 0; m < 4; ++m)
            a[m] = *(const bf16x8*)&Als[(wr * 64 + m * 16 + lr) * 40 + lk];
        #pragma unroll
        for (int n = 0; n < 4; ++n)
            b[n] = *(const bf16x8*)&Bls[(wc * 64 + n * 16 + lr) * 40 + lk];

        #pragma unroll
        for (int m = 0; m < 4; ++m)
            #pragma unroll
            for (int n = 0; n < 4; ++n)
                acc[m][n] = __builtin_amdgcn_mfma_f32_16x16x32_bf16(
                    a[m], b[n], acc[m][n], 0, 0, 0);
    }

    const int orow0 = brow + wr * 64 + ((l >> 4) << 2);
    const int ocol0 = bcol + wc * 64 + lr;
    #pragma unroll
    for (int n = 0; n < 4; ++n) {
        const int col = ocol0 + n * 16;
        const float bv = bias[col];
        #pragma unroll
        for (int m = 0; m < 4; ++m) {
            #pragma unroll
            for (int r = 0; r < 4; ++r) {
                const int row = orow0 + m * 16 + r;
                const float v = acc[m][n][r] + bv;
                if (OUT_BF16) outb[(size_t)row * N + col] = f2b(v);
                else          outf[(size_t)row * N + col] = v;
            }
        }
    }
}

// ---------------------------------------------------------------------------
// MFMA flash attention (causal). Block = 256 thr = 4 waves = one 64-row Q tile
// of one (b,h). Wave w owns q-rows [qt*64+w*16, +16). K tile + V^T tile staged
// in LDS (stride 72 u16 -> <=2-way banks). S in C/D regs; P via per-wave LDS.
//   A-frag (16xK rows=q):  lane reads row l&15, k-cols (l>>4)*8..+7
//   B-frag (BT rows=k/d):  lane reads row l&15, k-cols (l>>4)*8..+7
//   C/D:                   col = l&15, row = (l>>4)*4 + reg
// ---------------------------------------------------------------------------
__global__ __launch_bounds__(256) void attn_mfma_kernel(
    const u16* __restrict__ qkvb, const u16* __restrict__ vT,
    u16* __restrict__ yb)
{
    __shared__ u16 Ks[64 * 72];      // [k-row][d], pad 72
    __shared__ u16 Vs[64 * 72];      // [d-row][k], pad 72 (from vT)
    __shared__ u16 Ps[4][16 * 72];   // per-wave P: [q-local][k], pad 72

    const int tid = threadIdx.x;
    const int w   = tid >> 6;        // wave 0..3
    const int l   = tid & 63;
    const int l15 = l & 15;
    const int g   = l >> 4;          // lane group 0..3
    const int qt  = blockIdx.x;      // q tile 0..31
    const int bh  = blockIdx.y;
    const int b   = bh >> 4, h = bh & 15;

    const float S2 = 0.18033688f;    // 0.125 * log2(e)

    // Q A-frags (2 d-halves), loaded once from global
    const u16* Qp = qkvb + (size_t)(b * Tn + qt * 64 + w * 16 + l15) * (3 * Cn)
                    + h * HDn + g * 8;
    bf16x8 qf[2];
    qf[0] = *(const bf16x8*)(Qp);
    qf[1] = *(const bf16x8*)(Qp + 32);

    f32x4 O[4];
    float m[4], lsum[4];
    #pragma unroll
    for (int r = 0; r < 4; ++r) {
        O[r] = (f32x4){0.f, 0.f, 0.f, 0.f};
        m[r] = -INFINITY; lsum[r] = 0.f;
    }

    const u16* Kg = qkvb + (size_t)(b * Tn) * (3 * Cn) + Cn + h * HDn;
    const u16* Vg = vT + (size_t)(bh * HDn) * Tn;

    for (int kt = 0; kt <= qt; ++kt) {
        __syncthreads();   // prior tile's Ks/Vs reads complete
        // Stage K tile [64 k x 64 d] and V^T tile [64 d x 64 k]
        #pragma unroll
        for (int i = 0; i < 2; ++i) {
            const int c   = tid + (i << 8);  // 0..511
            const int row = c >> 3;          // 0..63
            const int ch  = (c & 7) << 3;    // 0,8,..,56
            *(us8*)&Ks[row * 72 + ch] =
                *(const us8*)&Kg[(size_t)(kt * 64 + row) * (3 * Cn) + ch];
            *(us8*)&Vs[row * 72 + ch] =
                *(const us8*)&Vg[(size_t)row * Tn + kt * 64 + ch];
        }
        __syncthreads();

        // S = Q K^T : 4 k-chunks x (2 mfma over d)
        f32x4 S[4];
        #pragma unroll
        for (int kc = 0; kc < 4; ++kc) {
            const bf16x8 k0 = *(const bf16x8*)&Ks[(kc * 16 + l15) * 72 + g * 8];
            const bf16x8 k1 = *(const bf16x8*)&Ks[(kc * 16 + l15) * 72 + 32 + g * 8];
            f32x4 acc = __builtin_amdgcn_mfma_f32_16x16x32_bf16(
                qf[0], k0, (f32x4){0.f, 0.f, 0.f, 0.f}, 0, 0, 0);
            S[kc] = __builtin_amdgcn_mfma_f32_16x16x32_bf16(qf[1], k1, acc, 0, 0, 0);
        }

        // Causal mask (diagonal tile only): valid iff k_loc <= w*16 + q_loc
        if (kt == qt) {
            #pragma unroll
            for (int kc = 0; kc < 4; ++kc)
                #pragma unroll
                for (int r = 0; r < 4; ++r)
                    if (kc * 16 + l15 > w * 16 + g * 4 + r)
                        S[kc][r] = -INFINITY;
        }

        // Row max across 4 frags + 16 lanes
        float mt[4];
        #pragma unroll
        for (int r = 0; r < 4; ++r)
            mt[r] = fmaxf(fmaxf(S[0][r], S[1][r]), fmaxf(S[2][r], S[3][r]));
        #pragma unroll
        for (int st = 1; st < 16; st <<= 1)
            #pragma unroll
            for (int r = 0; r < 4; ++r)
                mt[r] = fmaxf(mt[r], __shfl_xor(mt[r], st));

        float alpha[4], lt[4];
        #pragma unroll
        for (int r = 0; r < 4; ++r) {
            const float mn = fmaxf(m[r], mt[r]);
            alpha[r] = exp2f((m[r] - mn) * S2);
            m[r] = mn;
            lt[r] = 0.f;
        }

        // P = exp(S - m), write bf16 to per-wave LDS
        #pragma unroll
        for (int kc = 0; kc < 4; ++kc)
            #pragma unroll
            for (int r = 0; r < 4; ++r) {
                const float p = exp2f((S[kc][r] - m[r]) * S2);
                Ps[w][(g * 4 + r) * 72 + kc * 16 + l15] = f2b(p);
                lt[r] += p;
            }
        #pragma unroll
        for (int st = 1; st < 16; st <<= 1)
            #pragma unroll
            for (int r = 0; r < 4; ++r)
                lt[r] += __shfl_xor(lt[r], st);
        #pragma unroll
        for (int r = 0; r < 4; ++r)
            lsum[r] = lsum[r] * alpha[r] + lt[r];

        // O rescale
        #pragma unroll
        for (int dc = 0; dc < 4; ++dc)
            #pragma unroll
            for (int r = 0; r < 4; ++r)
                O[dc][r] *= alpha[r];

        // O += P @ V : A = P rows (q), B = Vs rows (d)
        #pragma unroll
        for (int hf = 0; hf < 2; ++hf) {
            const bf16x8 pf = *(const bf16x8*)&Ps[w][l15 * 72 + hf * 32 + g * 8];
            #pragma unroll
            for (int dc = 0; dc < 4; ++dc) {
                const bf16x8 vf =
                    *(const bf16x8*)&Vs[(dc * 16 + l15) * 72 + hf * 32 + g * 8];
                O[dc] = __builtin_amdgcn_mfma_f32_16x16x32_bf16(pf, vf, O[dc], 0, 0, 0);
            }
        }
    }

    // Epilogue: O /= l, write y (bf16)
    #pragma unroll
    for (int r = 0; r < 4; ++r) {
        const float inv = 1.f / lsum[r];
        const size_t ro =
            (size_t)(b * Tn + qt * 64 + w * 16 + g * 4 + r) * Cn + h * HDn;
        #pragma unroll
        for (int dc = 0; dc < 4; ++dc)
            yb[ro + dc * 16 + l15] = f2b(O[dc][r] * inv);
    }
}

// ---------------------------------------------------------------------------
extern "C" void kernel_launch(void* const* d_in, const int* in_sizes, int n_in,
                              void* d_out, int out_size, void* d_ws, size_t ws_size,
                              hipStream_t stream)
{
    const float* x      = (const float*)d_in[0];
    const float* W_attn = (const float*)d_in[1];
    const float* b_attn = (const float*)d_in[2];
    const float* W_proj = (const float*)d_in[3];
    const float* b_proj = (const float*)d_in[4];
    float* out = (float*)d_out;

    // Workspace (bf16): xb | WaT | WpT | qkvb | yb | vT  (~108 MB)
    u16* xb   = (u16*)d_ws;
    u16* WaT  = xb   + (size_t)Mn * Cn;
    u16* WpT  = WaT  + (size_t)3 * Cn * Cn;
    u16* qkvb = WpT  + (size_t)Cn * Cn;
    u16* yb   = qkvb + (size_t)Mn * 3 * Cn;
    u16* vT   = yb   + (size_t)Mn * Cn;

    cvt_f32_bf16_kernel<<<(Mn * Cn / 4 + 255) / 256, 256, 0, stream>>>(
        (const float4*)x, (ushort4*)xb, Mn * Cn / 4);

    transpose_cvt_kernel<<<dim3(3 * Cn / 32, Cn / 32), 256, 0, stream>>>(
        W_attn, WaT, Cn, 3 * Cn);
    transpose_cvt_kernel<<<dim3(Cn / 32, Cn / 32), 256, 0, stream>>>(
        W_proj, WpT, Cn, Cn);

    // qkv = x @ W_attn + b_attn (bf16 out)
    gemm_bf16_kernel<true><<<dim3(3 * Cn / 128, Mn / 128), 256, 0, stream>>>(
        xb, WaT, b_attn, qkvb, nullptr, 3 * Cn, Cn);

    // vT = transpose of V section (per-batch [T,C] -> [C,T])
    transpose_v_kernel<<<dim3(Cn / 32, Tn / 32, Bn), 256, 0, stream>>>(qkvb, vT);

    // causal MFMA attention -> yb (bf16)
    attn_mfma_kernel<<<dim3(Tn / 64, Bn * Hn), 256, 0, stream>>>(qkvb, vT, yb);

    // out = y @ W_proj + b_proj (f32 out)
    gemm_bf16_kernel<false><<<dim3(Cn / 128, Mn / 128), 256, 0, stream>>>(
        yb, WpT, b_proj, nullptr, out, Cn, Cn);
}

// Round 4
// 240.908 us; speedup vs baseline: 14.4852x; 1.5666x over previous
//
#include <hip/hip_runtime.h>
#include <math.h>

// Problem constants
#define Bn 4
#define Tn 2048
#define Cn 1024
#define Hn 16
#define HDn 64
#define Mn (Bn * Tn)  // 8192 tokens

typedef unsigned short u16;
typedef unsigned int u32;
typedef __attribute__((ext_vector_type(8))) short bf16x8;        // 8 bf16 = 4 VGPRs
typedef __attribute__((ext_vector_type(8))) unsigned short us8;  // 16B chunk
typedef __attribute__((ext_vector_type(4))) float f32x4;         // MFMA accumulator

__device__ __forceinline__ float b2f(u16 u) {
    return __uint_as_float(((u32)u) << 16);
}
__device__ __forceinline__ u16 f2b(float f) {
    u32 u = __float_as_uint(f);
    return (u16)((u + 0x7FFFu + ((u >> 16) & 1u)) >> 16);  // RNE
}
__device__ __forceinline__ u16 f2b_fast(float f) {
    return (u16)((__float_as_uint(f) + 0x8000u) >> 16);    // round-half-up
}

#if __has_builtin(__builtin_amdgcn_global_load_lds)
#define GLD_LDS_OK 1
#else
#define GLD_LDS_OK 0
#endif

// ---------------------------------------------------------------------------
// fp32 -> bf16 elementwise convert
// ---------------------------------------------------------------------------
__global__ __launch_bounds__(256) void cvt_f32_bf16_kernel(
    const float4* __restrict__ in, ushort4* __restrict__ out, int n4)
{
    int i = blockIdx.x * 256 + threadIdx.x;
    if (i < n4) {
        float4 v = in[i];
        ushort4 o;
        o.x = f2b(v.x); o.y = f2b(v.y); o.z = f2b(v.z); o.w = f2b(v.w);
        out[i] = o;
    }
}

// ---------------------------------------------------------------------------
// Transpose + convert: in [R,Cc] fp32 -> out [Cc,R] bf16. 32x32 LDS tiles.
// ---------------------------------------------------------------------------
__global__ __launch_bounds__(256) void transpose_cvt_kernel(
    const float* __restrict__ in, u16* __restrict__ out, int R, int Cc)
{
    __shared__ u16 t[32][33];
    const int c0 = blockIdx.x * 32, r0 = blockIdx.y * 32;
    const int tx = threadIdx.x & 31, ty = threadIdx.x >> 5;  // 32 x 8
    #pragma unroll
    for (int i = 0; i < 32; i += 8)
        t[ty + i][tx] = f2b(in[(size_t)(r0 + ty + i) * Cc + c0 + tx]);
    __syncthreads();
    #pragma unroll
    for (int i = 0; i < 32; i += 8)
        out[(size_t)(c0 + ty + i) * R + r0 + tx] = t[tx][ty + i];
}

// ---------------------------------------------------------------------------
// V transpose: qkv V-section [B][T][C] bf16 -> vT [B][C][T] bf16.
// ---------------------------------------------------------------------------
__global__ __launch_bounds__(256) void transpose_v_kernel(
    const u16* __restrict__ qkvb, u16* __restrict__ vT)
{
    __shared__ u16 t[32][33];
    const int c0 = blockIdx.x * 32, t0 = blockIdx.y * 32, b = blockIdx.z;
    const int tx = threadIdx.x & 31, ty = threadIdx.x >> 5;  // 32 x 8
    #pragma unroll
    for (int i = 0; i < 32; i += 8)
        t[ty + i][tx] =
            qkvb[(size_t)(b * Tn + t0 + ty + i) * (3 * Cn) + 2 * Cn + c0 + tx];
    __syncthreads();
    #pragma unroll
    for (int i = 0; i < 32; i += 8)
        vT[(size_t)(b * Cn + c0 + ty + i) * Tn + t0 + tx] = t[tx][ty + i];
}

// ---------------------------------------------------------------------------
// bf16 MFMA GEMM (m97 structure): Out[M,N] = A[M,K] @ BT[N,K]^T + bias[N]
// 128x128 tile, BK=32, 4 waves. Staging via global_load_lds width=16 into
// LINEAR LDS [128][32] (wave-uniform base + lane*16). Frag reads ds_read_b128.
// ---------------------------------------------------------------------------
template <bool OUT_BF16>
__global__ __launch_bounds__(256) void gemm_bf16_kernel(
    const u16* __restrict__ A, const u16* __restrict__ BT,
    const float* __restrict__ bias,
    u16* __restrict__ outb, float* __restrict__ outf,
    int N, int K)
{
    __shared__ u16 Al[128 * 32];
    __shared__ u16 Bl[128 * 32];

    const int tid = threadIdx.x;
    const int brow = blockIdx.y * 128;
    const int bcol = blockIdx.x * 128;
    const int w  = tid >> 6;
    const int wr = w >> 1, wc = w & 1;
    const int l  = tid & 63;
    const int lr = l & 15;
    const int lk = (l >> 4) << 3;

    f32x4 acc[4][4];
    #pragma unroll
    for (int m = 0; m < 4; ++m)
        #pragma unroll
        for (int n = 0; n < 4; ++n) acc[m][n] = (f32x4){0.f, 0.f, 0.f, 0.f};

    for (int k0 = 0; k0 < K; k0 += 32) {
        __syncthreads();  // protect prior iteration's fragment reads
        #pragma unroll
        for (int i = 0; i < 2; ++i) {
            const int c   = i * 256 + tid;    // chunk 0..511
            const int row = c >> 2;           // 0..127
            const int col = (c & 3) << 3;     // 0,8,16,24
#if GLD_LDS_OK
            // LDS dest: wave-uniform base + lane*16B (linear layout required)
            __builtin_amdgcn_global_load_lds(
                (const __attribute__((address_space(1))) u32*)
                    &A[(size_t)(brow + row) * K + k0 + col],
                (__attribute__((address_space(3))) u32*)
                    &Al[(size_t)(i * 256 + (tid & 192)) * 8],
                16, 0, 0);
            __builtin_amdgcn_global_load_lds(
                (const __attribute__((address_space(1))) u32*)
                    &BT[(size_t)(bcol + row) * K + k0 + col],
                (__attribute__((address_space(3))) u32*)
                    &Bl[(size_t)(i * 256 + (tid & 192)) * 8],
                16, 0, 0);
#else
            *(us8*)&Al[(size_t)c * 8] = *(const us8*)&A [(size_t)(brow + row) * K + k0 + col];
            *(us8*)&Bl[(size_t)c * 8] = *(const us8*)&BT[(size_t)(bcol + row) * K + k0 + col];
#endif
        }
        __syncthreads();

        bf16x8 a[4], b[4];
        #pragma unroll
        for (int m = 0; m < 4; ++m)
            a[m] = *(const bf16x8*)&Al[(wr * 64 + m * 16 + lr) * 32 + lk];
        #pragma unroll
        for (int n = 0; n < 4; ++n)
            b[n] = *(const bf16x8*)&Bl[(wc * 64 + n * 16 + lr) * 32 + lk];

        __builtin_amdgcn_s_setprio(1);
        #pragma unroll
        for (int m = 0; m < 4; ++m)
            #pragma unroll
            for (int n = 0; n < 4; ++n)
                acc[m][n] = __builtin_amdgcn_mfma_f32_16x16x32_bf16(
                    a[m], b[n], acc[m][n], 0, 0, 0);
        __builtin_amdgcn_s_setprio(0);
    }

    // Epilogue. C/D layout: col = lane&15, row = (lane>>4)*4 + reg.
    const int orow0 = brow + wr * 64 + ((l >> 4) << 2);
    const int ocol0 = bcol + wc * 64 + lr;
    #pragma unroll
    for (int n = 0; n < 4; ++n) {
        const int col = ocol0 + n * 16;
        const float bv = bias[col];
        #pragma unroll
        for (int m = 0; m < 4; ++m) {
            #pragma unroll
            for (int r = 0; r < 4; ++r) {
                const int row = orow0 + m * 16 + r;
                const float v = acc[m][n][r] + bv;
                if (OUT_BF16) outb[(size_t)row * N + col] = f2b(v);
                else          outf[(size_t)row * N + col] = v;
            }
        }
    }
}

// ---------------------------------------------------------------------------
// MFMA flash attention v2 (causal).
// Block = 256 thr = 4 waves; processes TWO q-tiles {p, 31-p} -> uniform 33
// tile-units per block; grid 16 x 64 = 1024 blocks = 4/CU, all resident.
// Swapped QK^T: S^T = mfma(A=K, B=Q) -> lane l15 = q-row, in-lane k-values
//   (row = k-local kc*16 + g*4 + r). Row-reduce = in-lane tree + 2 shuffles.
// Async-STAGE split (T14): next tile's K/V global loads issued before QK^T,
//   LDS writes after the barrier -> HBM latency hides under compute.
// Defer-max (T13, THR=8 -> 64 in raw-S units).
// ---------------------------------------------------------------------------
__global__ __launch_bounds__(256) void attn_mfma2_kernel(
    const u16* __restrict__ qkvb, const u16* __restrict__ vT,
    u16* __restrict__ yb)
{
    __shared__ u16 Ks[64 * 72];      // [k-row][d], pad 72 (144B, 16B-aligned)
    __shared__ u16 Vs[64 * 72];      // [d-row][k], pad 72 (from vT)
    __shared__ u16 Ps[4][16 * 72];   // per-wave P: [q-local][k]

    const int tid = threadIdx.x;
    const int w   = tid >> 6;        // wave 0..3
    const int l   = tid & 63;
    const int l15 = l & 15;
    const int g   = l >> 4;          // lane group 0..3
    const int pr  = blockIdx.x;      // pair index 0..15
    const int bh  = blockIdx.y;
    const int b   = bh >> 4, h = bh & 15;

    const float S2 = 0.18033688f;    // 0.125 * log2(e)

    const u16* Kg = qkvb + (size_t)(b * Tn) * (3 * Cn) + Cn + h * HDn;
    const u16* Vg = vT + (size_t)bh * HDn * Tn;

    for (int half = 0; half < 2; ++half) {
        const int qt = half ? (31 - pr) : pr;
        const int qglob = qt * 64 + w * 16 + l15;

        // Q B-frags (2 d-halves)
        const u16* Qp = qkvb + (size_t)(b * Tn + qt * 64 + w * 16 + l15) * (3 * Cn)
                        + h * HDn + g * 8;
        const bf16x8 qf0 = *(const bf16x8*)(Qp);
        const bf16x8 qf1 = *(const bf16x8*)(Qp + 32);

        f32x4 O[4];
        float m = -INFINITY, lsum = 0.f;
        #pragma unroll
        for (int dc = 0; dc < 4; ++dc) O[dc] = (f32x4){0.f, 0.f, 0.f, 0.f};

        // ---- stage tile 0 (reg -> barrier -> LDS) ----
        us8 kr[2], vr[2];
        #pragma unroll
        for (int i = 0; i < 2; ++i) {
            const int c = i * 256 + tid, row = c >> 3, ch = (c & 7) << 3;
            kr[i] = *(const us8*)&Kg[(size_t)row * (3 * Cn) + ch];
            vr[i] = *(const us8*)&Vg[(size_t)row * Tn + ch];
        }
        __syncthreads();  // prior half's LDS reads complete
        #pragma unroll
        for (int i = 0; i < 2; ++i) {
            const int c = i * 256 + tid, row = c >> 3, ch = (c & 7) << 3;
            *(us8*)&Ks[row * 72 + ch] = kr[i];
            *(us8*)&Vs[row * 72 + ch] = vr[i];
        }
        __syncthreads();

        for (int kt = 0; kt <= qt; ++kt) {
            // issue next tile's global loads early (latency hides under compute)
            if (kt < qt) {
                #pragma unroll
                for (int i = 0; i < 2; ++i) {
                    const int c = i * 256 + tid, row = c >> 3, ch = (c & 7) << 3;
                    kr[i] = *(const us8*)&Kg[(size_t)((kt + 1) * 64 + row) * (3 * Cn) + ch];
                    vr[i] = *(const us8*)&Vg[(size_t)row * Tn + (kt + 1) * 64 + ch];
                }
            }

            // S^T = K Q^T : row = k-local, col = q (l15)
            f32x4 S[4];
            __builtin_amdgcn_s_setprio(1);
            #pragma unroll
            for (int kc = 0; kc < 4; ++kc) {
                const bf16x8 k0 = *(const bf16x8*)&Ks[(kc * 16 + l15) * 72 + g * 8];
                const bf16x8 k1 = *(const bf16x8*)&Ks[(kc * 16 + l15) * 72 + 32 + g * 8];
                f32x4 z = (f32x4){0.f, 0.f, 0.f, 0.f};
                z = __builtin_amdgcn_mfma_f32_16x16x32_bf16(k0, qf0, z, 0, 0, 0);
                S[kc] = __builtin_amdgcn_mfma_f32_16x16x32_bf16(k1, qf1, z, 0, 0, 0);
            }
            __builtin_amdgcn_s_setprio(0);

            // causal mask (diagonal tile only): k = kt*64 + kc*16 + g*4 + r
            if (kt == qt) {
                #pragma unroll
                for (int kc = 0; kc < 4; ++kc)
                    #pragma unroll
                    for (int r = 0; r < 4; ++r)
                        if (qt * 64 + kc * 16 + g * 4 + r > qglob)
                            S[kc][r] = -INFINITY;
            }

            // row max: in-lane tree (max3-fusable) + 2 shuffles across g
            float m01 = fmaxf(fmaxf(S[0][0], S[0][1]), fmaxf(S[0][2], S[0][3]));
            float m23 = fmaxf(fmaxf(S[1][0], S[1][1]), fmaxf(S[1][2], S[1][3]));
            float m45 = fmaxf(fmaxf(S[2][0], S[2][1]), fmaxf(S[2][2], S[2][3]));
            float m67 = fmaxf(fmaxf(S[3][0], S[3][1]), fmaxf(S[3][2], S[3][3]));
            float mt = fmaxf(fmaxf(m01, m23), fmaxf(m45, m67));
            mt = fmaxf(mt, __shfl_xor(mt, 16));
            mt = fmaxf(mt, __shfl_xor(mt, 32));

            // defer-max: only rescale when max grew by > 64 raw (= 8 post-scale)
            float lscale = 1.f;
            if (__any(!(mt <= m + 64.f))) {
                const float mn = fmaxf(m, mt);
                const float alpha = exp2f((m - mn) * S2);
                m = mn;
                float aO[4];
                #pragma unroll
                for (int r = 0; r < 4; ++r) aO[r] = __shfl(alpha, g * 4 + r);
                #pragma unroll
                for (int dc = 0; dc < 4; ++dc)
                    #pragma unroll
                    for (int r = 0; r < 4; ++r) O[dc][r] *= aO[r];
                lscale = alpha;
            }

            // P = exp(S - m) (bounded by e^8), pack 4 -> 8B LDS write
            float lt = 0.f;
            #pragma unroll
            for (int kc = 0; kc < 4; ++kc) {
                const float p0 = exp2f((S[kc][0] - m) * S2);
                const float p1 = exp2f((S[kc][1] - m) * S2);
                const float p2 = exp2f((S[kc][2] - m) * S2);
                const float p3 = exp2f((S[kc][3] - m) * S2);
                lt += (p0 + p1) + (p2 + p3);
                ushort4 pk;
                pk.x = f2b_fast(p0); pk.y = f2b_fast(p1);
                pk.z = f2b_fast(p2); pk.w = f2b_fast(p3);
                *(ushort4*)&Ps[w][l15 * 72 + kc * 16 + g * 4] = pk;
            }
            lt += __shfl_xor(lt, 16);
            lt += __shfl_xor(lt, 32);
            lsum = lsum * lscale + lt;

            // O += P @ V : A = P rows (q), B = Vs rows (d)
            __builtin_amdgcn_s_setprio(1);
            #pragma unroll
            for (int hf = 0; hf < 2; ++hf) {
                const bf16x8 pf = *(const bf16x8*)&Ps[w][l15 * 72 + hf * 32 + g * 8];
                #pragma unroll
                for (int dc = 0; dc < 4; ++dc) {
                    const bf16x8 vf =
                        *(const bf16x8*)&Vs[(dc * 16 + l15) * 72 + hf * 32 + g * 8];
                    O[dc] = __builtin_amdgcn_mfma_f32_16x16x32_bf16(pf, vf, O[dc], 0, 0, 0);
                }
            }
            __builtin_amdgcn_s_setprio(0);

            // write staged next tile to LDS
            if (kt < qt) {
                __syncthreads();  // all waves done reading Ks/Vs
                #pragma unroll
                for (int i = 0; i < 2; ++i) {
                    const int c = i * 256 + tid, row = c >> 3, ch = (c & 7) << 3;
                    *(us8*)&Ks[row * 72 + ch] = kr[i];
                    *(us8*)&Vs[row * 72 + ch] = vr[i];
                }
                __syncthreads();
            }
        }

        // epilogue: O rows are g*4+r; fetch their lsum via shuffle
        #pragma unroll
        for (int r = 0; r < 4; ++r) {
            const float ls = __shfl(lsum, g * 4 + r);
            const float inv = 1.f / ls;
            const size_t ro =
                (size_t)(b * Tn + qt * 64 + w * 16 + g * 4 + r) * Cn + h * HDn;
            #pragma unroll
            for (int dc = 0; dc < 4; ++dc)
                yb[ro + dc * 16 + l15] = f2b(O[dc][r] * inv);
        }
    }
}

// ---------------------------------------------------------------------------
extern "C" void kernel_launch(void* const* d_in, const int* in_sizes, int n_in,
                              void* d_out, int out_size, void* d_ws, size_t ws_size,
                              hipStream_t stream)
{
    const float* x      = (const float*)d_in[0];
    const float* W_attn = (const float*)d_in[1];
    const float* b_attn = (const float*)d_in[2];
    const float* W_proj = (const float*)d_in[3];
    const float* b_proj = (const float*)d_in[4];
    float* out = (float*)d_out;

    // Workspace (bf16): xb | WaT | WpT | qkvb | yb | vT  (~108 MB)
    u16* xb   = (u16*)d_ws;
    u16* WaT  = xb   + (size_t)Mn * Cn;
    u16* WpT  = WaT  + (size_t)3 * Cn * Cn;
    u16* qkvb = WpT  + (size_t)Cn * Cn;
    u16* yb   = qkvb + (size_t)Mn * 3 * Cn;
    u16* vT   = yb   + (size_t)Mn * Cn;

    cvt_f32_bf16_kernel<<<(Mn * Cn / 4 + 255) / 256, 256, 0, stream>>>(
        (const float4*)x, (ushort4*)xb, Mn * Cn / 4);

    transpose_cvt_kernel<<<dim3(3 * Cn / 32, Cn / 32), 256, 0, stream>>>(
        W_attn, WaT, Cn, 3 * Cn);
    transpose_cvt_kernel<<<dim3(Cn / 32, Cn / 32), 256, 0, stream>>>(
        W_proj, WpT, Cn, Cn);

    // qkv = x @ W_attn + b_attn (bf16 out)
    gemm_bf16_kernel<true><<<dim3(3 * Cn / 128, Mn / 128), 256, 0, stream>>>(
        xb, WaT, b_attn, qkvb, nullptr, 3 * Cn, Cn);

    // vT = per-batch transpose of V section ([T,C] -> [C,T])
    transpose_v_kernel<<<dim3(Cn / 32, Tn / 32, Bn), 256, 0, stream>>>(qkvb, vT);

    // causal MFMA attention -> yb (bf16); paired q-tiles for uniform work
    attn_mfma2_kernel<<<dim3(Tn / 128, Bn * Hn), 256, 0, stream>>>(qkvb, vT, yb);

    // out = y @ W_proj + b_proj (f32 out)
    gemm_bf16_kernel<false><<<dim3(Cn / 128, Mn / 128), 256, 0, stream>>>(
        yb, WpT, b_proj, nullptr, out, Cn, Cn);
}

// Round 5
// 227.001 us; speedup vs baseline: 15.3726x; 1.0613x over previous
//
#include <hip/hip_runtime.h>
#include <math.h>

// Problem constants
#define Bn 4
#define Tn 2048
#define Cn 1024
#define Hn 16
#define HDn 64
#define Mn (Bn * Tn)  // 8192 tokens

typedef unsigned short u16;
typedef unsigned int u32;
typedef __attribute__((ext_vector_type(8))) short bf16x8;        // 8 bf16 = 4 VGPRs
typedef __attribute__((ext_vector_type(8))) unsigned short us8;  // 16B chunk
typedef __attribute__((ext_vector_type(4))) float f32x4;         // MFMA accumulator

__device__ __forceinline__ float b2f(u16 u) {
    return __uint_as_float(((u32)u) << 16);
}
__device__ __forceinline__ u16 f2b(float f) {
    u32 u = __float_as_uint(f);
    return (u16)((u + 0x7FFFu + ((u >> 16) & 1u)) >> 16);  // RNE
}
__device__ __forceinline__ u16 f2b_fast(float f) {
    return (u16)((__float_as_uint(f) + 0x8000u) >> 16);    // round-half-up
}

// XCD-grouped work id from flat block id (requires gridDim.x % 8 == 0).
// Blocks with equal (bid & 7) land on one XCD (round-robin model) and get a
// contiguous chunk of the work space -> L2 locality for shared panels.
__device__ __forceinline__ int xcd_work(int bid, int nwg) {
    return (bid & 7) * (nwg >> 3) + (bid >> 3);
}

// ---------------------------------------------------------------------------
// fp32 -> bf16 elementwise convert
// ---------------------------------------------------------------------------
__global__ __launch_bounds__(256) void cvt_f32_bf16_kernel(
    const float4* __restrict__ in, ushort4* __restrict__ out, int n4)
{
    int i = blockIdx.x * 256 + threadIdx.x;
    if (i < n4) {
        float4 v = in[i];
        ushort4 o;
        o.x = f2b(v.x); o.y = f2b(v.y); o.z = f2b(v.z); o.w = f2b(v.w);
        out[i] = o;
    }
}

// ---------------------------------------------------------------------------
// Transpose + convert: in [R,Cc] fp32 -> out [Cc,R] bf16. 32x32 LDS tiles.
// ---------------------------------------------------------------------------
__global__ __launch_bounds__(256) void transpose_cvt_kernel(
    const float* __restrict__ in, u16* __restrict__ out, int R, int Cc)
{
    __shared__ u16 t[32][33];
    const int c0 = blockIdx.x * 32, r0 = blockIdx.y * 32;
    const int tx = threadIdx.x & 31, ty = threadIdx.x >> 5;  // 32 x 8
    #pragma unroll
    for (int i = 0; i < 32; i += 8)
        t[ty + i][tx] = f2b(in[(size_t)(r0 + ty + i) * Cc + c0 + tx]);
    __syncthreads();
    #pragma unroll
    for (int i = 0; i < 32; i += 8)
        out[(size_t)(c0 + ty + i) * R + r0 + tx] = t[tx][ty + i];
}

// ---------------------------------------------------------------------------
// V transpose: qkv V-section [B][T][C] bf16 -> vT [B][C][T] bf16.
// ---------------------------------------------------------------------------
__global__ __launch_bounds__(256) void transpose_v_kernel(
    const u16* __restrict__ qkvb, u16* __restrict__ vT)
{
    __shared__ u16 t[32][33];
    const int c0 = blockIdx.x * 32, t0 = blockIdx.y * 32, b = blockIdx.z;
    const int tx = threadIdx.x & 31, ty = threadIdx.x >> 5;  // 32 x 8
    #pragma unroll
    for (int i = 0; i < 32; i += 8)
        t[ty + i][tx] =
            qkvb[(size_t)(b * Tn + t0 + ty + i) * (3 * Cn) + 2 * Cn + c0 + tx];
    __syncthreads();
    #pragma unroll
    for (int i = 0; i < 32; i += 8)
        vT[(size_t)(b * Cn + c0 + ty + i) * Tn + t0 + tx] = t[tx][ty + i];
}

// ---------------------------------------------------------------------------
// bf16 MFMA GEMM (m97 structure): Out[M,N] = A[M,K] @ BT[N,K]^T + bias[N]
// 128x128 tile, BK=32, 4 waves, global_load_lds width=16 staging, flat grid
// with XCD-grouped work remap.
// ---------------------------------------------------------------------------
template <bool OUT_BF16>
__global__ __launch_bounds__(256) void gemm_bf16_kernel(
    const u16* __restrict__ A, const u16* __restrict__ BT,
    const float* __restrict__ bias,
    u16* __restrict__ outb, float* __restrict__ outf,
    int N, int K, int nx)
{
    __shared__ u16 Al[128 * 32];
    __shared__ u16 Bl[128 * 32];

    const int tid = threadIdx.x;
    const int workid = xcd_work(blockIdx.x, gridDim.x);
    const int brow = (workid / nx) * 128;
    const int bcol = (workid % nx) * 128;
    const int w  = tid >> 6;
    const int wr = w >> 1, wc = w & 1;
    const int l  = tid & 63;
    const int lr = l & 15;
    const int lk = (l >> 4) << 3;

    f32x4 acc[4][4];
    #pragma unroll
    for (int m = 0; m < 4; ++m)
        #pragma unroll
        for (int n = 0; n < 4; ++n) acc[m][n] = (f32x4){0.f, 0.f, 0.f, 0.f};

    for (int k0 = 0; k0 < K; k0 += 32) {
        __syncthreads();  // protect prior iteration's fragment reads
        #pragma unroll
        for (int i = 0; i < 2; ++i) {
            const int c   = i * 256 + tid;    // chunk 0..511
            const int row = c >> 2;           // 0..127
            const int col = (c & 3) << 3;     // 0,8,16,24
            __builtin_amdgcn_global_load_lds(
                (const __attribute__((address_space(1))) u32*)
                    &A[(size_t)(brow + row) * K + k0 + col],
                (__attribute__((address_space(3))) u32*)
                    &Al[(size_t)(i * 256 + (tid & 192)) * 8],
                16, 0, 0);
            __builtin_amdgcn_global_load_lds(
                (const __attribute__((address_space(1))) u32*)
                    &BT[(size_t)(bcol + row) * K + k0 + col],
                (__attribute__((address_space(3))) u32*)
                    &Bl[(size_t)(i * 256 + (tid & 192)) * 8],
                16, 0, 0);
        }
        __syncthreads();

        bf16x8 a[4], b[4];
        #pragma unroll
        for (int m = 0; m < 4; ++m)
            a[m] = *(const bf16x8*)&Al[(wr * 64 + m * 16 + lr) * 32 + lk];
        #pragma unroll
        for (int n = 0; n < 4; ++n)
            b[n] = *(const bf16x8*)&Bl[(wc * 64 + n * 16 + lr) * 32 + lk];

        __builtin_amdgcn_s_setprio(1);
        #pragma unroll
        for (int m = 0; m < 4; ++m)
            #pragma unroll
            for (int n = 0; n < 4; ++n)
                acc[m][n] = __builtin_amdgcn_mfma_f32_16x16x32_bf16(
                    a[m], b[n], acc[m][n], 0, 0, 0);
        __builtin_amdgcn_s_setprio(0);
    }

    // Epilogue. C/D layout: col = lane&15, row = (lane>>4)*4 + reg.
    const int orow0 = brow + wr * 64 + ((l >> 4) << 2);
    const int ocol0 = bcol + wc * 64 + lr;
    #pragma unroll
    for (int n = 0; n < 4; ++n) {
        const int col = ocol0 + n * 16;
        const float bv = bias[col];
        #pragma unroll
        for (int m = 0; m < 4; ++m) {
            #pragma unroll
            for (int r = 0; r < 4; ++r) {
                const int row = orow0 + m * 16 + r;
                const float v = acc[m][n][r] + bv;
                if (OUT_BF16) outb[(size_t)row * N + col] = f2b(v);
                else          outf[(size_t)row * N + col] = v;
            }
        }
    }
}

// ---------------------------------------------------------------------------
// MFMA flash attention v3 (causal).
// Block = 4 waves = one 64-row Q tile; paired q-tiles {p, 31-p} (uniform work).
// Flat grid 1024, XCD-grouped: each XCD owns 8 full (b,h) heads -> K/V L2-fit.
// K/V staged via global_load_lds into double-buffered LINEAR [64][64] LDS with
// both-sides XOR swizzle (chunk ^= row&7): DMA source pre-swizzled, reads
// apply the same key -> <=2-way banks. ONE barrier per tile (T3 min form).
// Swapped QK^T (S^T = mfma(K,Q)), defer-max (T13), setprio (T5).
// ---------------------------------------------------------------------------
__global__ __launch_bounds__(256) void attn_mfma3_kernel(
    const u16* __restrict__ qkvb, const u16* __restrict__ vT,
    u16* __restrict__ yb)
{
    __shared__ u16 Kb[2][64 * 64];   // [k-row][d-chunk swizzled]
    __shared__ u16 Vb[2][64 * 64];   // [d-row][k-chunk swizzled]
    __shared__ u16 Ps[4][16 * 64];   // per-wave P, same swizzle

    const int tid = threadIdx.x;
    const int w   = tid >> 6;        // wave 0..3
    const int l   = tid & 63;
    const int l15 = l & 15;
    const int g   = l >> 4;          // lane group 0..3
    const int work = xcd_work(blockIdx.x, 1024);
    const int pr  = work & 15;       // pair index 0..15
    const int bh  = work >> 4;       // bh-major -> 8 bh per XCD
    const int b   = bh >> 4, h = bh & 15;

    const float S2 = 0.18033688f;    // 0.125 * log2(e)

    const u16* Kg = qkvb + (size_t)(b * Tn) * (3 * Cn) + Cn + h * HDn;
    const u16* Vg = vT + (size_t)bh * HDn * Tn;

    // staging decomposition: lane covers (row-in-8-group, chunk)
    const int srow = l >> 3;                   // 0..7
    const int schk = ((l & 7) ^ srow) << 3;    // swizzled source chunk (u16 off)
    const int rloc = w * 16;                   // wave's 16-row slice of tile

    const int rsw = (l15 & 7) << 3;            // read-side XOR key (u16)

    for (int half = 0; half < 2; ++half) {
        const int qt = half ? (31 - pr) : pr;
        const int qglob = qt * 64 + w * 16 + l15;

        // Q B-frags (2 d-halves)
        const u16* Qp = qkvb + (size_t)(b * Tn + qt * 64 + w * 16 + l15) * (3 * Cn)
                        + h * HDn + (g << 3);
        const bf16x8 qf0 = *(const bf16x8*)(Qp);
        const bf16x8 qf1 = *(const bf16x8*)(Qp + 32);

        f32x4 O[4];
        float m = -INFINITY, lsum = 0.f;
        #pragma unroll
        for (int dc = 0; dc < 4; ++dc) O[dc] = (f32x4){0.f, 0.f, 0.f, 0.f};

        // prologue: stage tile 0 -> buf 0 (DMA; barrier drains vmcnt)
        #pragma unroll
        for (int jc = 0; jc < 2; ++jc) {
            const int rr = rloc + jc * 8;
            __builtin_amdgcn_global_load_lds(
                (const __attribute__((address_space(1))) u32*)
                    (Kg + (size_t)(rr + srow) * (3 * Cn) + schk),
                (__attribute__((address_space(3))) u32*)&Kb[0][rr * 64], 16, 0, 0);
            __builtin_amdgcn_global_load_lds(
                (const __attribute__((address_space(1))) u32*)
                    (Vg + (size_t)(rr + srow) * Tn + schk),
                (__attribute__((address_space(3))) u32*)&Vb[0][rr * 64], 16, 0, 0);
        }
        __syncthreads();

        int cur = 0;
        for (int kt = 0; kt <= qt; ++kt) {
            // issue next tile's DMA into buf^1 (lands during this tile's compute)
            if (kt < qt) {
                #pragma unroll
                for (int jc = 0; jc < 2; ++jc) {
                    const int rr = rloc + jc * 8;
                    __builtin_amdgcn_global_load_lds(
                        (const __attribute__((address_space(1))) u32*)
                            (Kg + (size_t)((kt + 1) * 64 + rr + srow) * (3 * Cn) + schk),
                        (__attribute__((address_space(3))) u32*)
                            &Kb[cur ^ 1][rr * 64], 16, 0, 0);
                    __builtin_amdgcn_global_load_lds(
                        (const __attribute__((address_space(1))) u32*)
                            (Vg + (size_t)(rr + srow) * Tn + (kt + 1) * 64 + schk),
                        (__attribute__((address_space(3))) u32*)
                            &Vb[cur ^ 1][rr * 64], 16, 0, 0);
                }
            }
            const u16* Kc = Kb[cur];
            const u16* Vc = Vb[cur];

            // S^T = K Q^T : row = k-local, col = q (l15)
            f32x4 S[4];
            __builtin_amdgcn_s_setprio(1);
            #pragma unroll
            for (int kc = 0; kc < 4; ++kc) {
                const bf16x8 k0 =
                    *(const bf16x8*)&Kc[(kc * 16 + l15) * 64 + ((g << 3) ^ rsw)];
                const bf16x8 k1 =
                    *(const bf16x8*)&Kc[(kc * 16 + l15) * 64 + ((32 + (g << 3)) ^ rsw)];
                f32x4 z = (f32x4){0.f, 0.f, 0.f, 0.f};
                z = __builtin_amdgcn_mfma_f32_16x16x32_bf16(k0, qf0, z, 0, 0, 0);
                S[kc] = __builtin_amdgcn_mfma_f32_16x16x32_bf16(k1, qf1, z, 0, 0, 0);
            }
            __builtin_amdgcn_s_setprio(0);

            // causal mask (diagonal tile only): k = kt*64 + kc*16 + g*4 + r
            if (kt == qt) {
                #pragma unroll
                for (int kc = 0; kc < 4; ++kc)
                    #pragma unroll
                    for (int r = 0; r < 4; ++r)
                        if (qt * 64 + kc * 16 + g * 4 + r > qglob)
                            S[kc][r] = -INFINITY;
            }

            // row max: in-lane tree + 2 shuffles across g
            float m01 = fmaxf(fmaxf(S[0][0], S[0][1]), fmaxf(S[0][2], S[0][3]));
            float m23 = fmaxf(fmaxf(S[1][0], S[1][1]), fmaxf(S[1][2], S[1][3]));
            float m45 = fmaxf(fmaxf(S[2][0], S[2][1]), fmaxf(S[2][2], S[2][3]));
            float m67 = fmaxf(fmaxf(S[3][0], S[3][1]), fmaxf(S[3][2], S[3][3]));
            float mt = fmaxf(fmaxf(m01, m23), fmaxf(m45, m67));
            mt = fmaxf(mt, __shfl_xor(mt, 16));
            mt = fmaxf(mt, __shfl_xor(mt, 32));

            // defer-max: rescale only when max grew by > 64 raw (= 8 post-scale)
            float lscale = 1.f;
            if (__any(!(mt <= m + 64.f))) {
                const float mn = fmaxf(m, mt);
                const float alpha = exp2f((m - mn) * S2);
                m = mn;
                float aO[4];
                #pragma unroll
                for (int r = 0; r < 4; ++r) aO[r] = __shfl(alpha, g * 4 + r);
                #pragma unroll
                for (int dc = 0; dc < 4; ++dc)
                    #pragma unroll
                    for (int r = 0; r < 4; ++r) O[dc][r] *= aO[r];
                lscale = alpha;
            }

            // P = exp(S - m), pack 4 -> 8B swizzled LDS write
            float lt = 0.f;
            #pragma unroll
            for (int kc = 0; kc < 4; ++kc) {
                const float p0 = exp2f((S[kc][0] - m) * S2);
                const float p1 = exp2f((S[kc][1] - m) * S2);
                const float p2 = exp2f((S[kc][2] - m) * S2);
                const float p3 = exp2f((S[kc][3] - m) * S2);
                lt += (p0 + p1) + (p2 + p3);
                ushort4 pk;
                pk.x = f2b_fast(p0); pk.y = f2b_fast(p1);
                pk.z = f2b_fast(p2); pk.w = f2b_fast(p3);
                *(ushort4*)&Ps[w][(l15 << 6) + (((kc << 4) + (g << 2)) ^ rsw)] = pk;
            }
            lt += __shfl_xor(lt, 16);
            lt += __shfl_xor(lt, 32);
            lsum = lsum * lscale + lt;

            // O += P @ V : A = P rows (q), B = Vs rows (d)
            __builtin_amdgcn_s_setprio(1);
            #pragma unroll
            for (int hf = 0; hf < 2; ++hf) {
                const bf16x8 pf =
                    *(const bf16x8*)&Ps[w][(l15 << 6) + (((hf << 5) + (g << 3)) ^ rsw)];
                #pragma unroll
                for (int dc = 0; dc < 4; ++dc) {
                    const bf16x8 vf = *(const bf16x8*)
                        &Vc[(dc * 16 + l15) * 64 + ((((hf << 2) + g) << 3) ^ rsw)];
                    O[dc] = __builtin_amdgcn_mfma_f32_16x16x32_bf16(pf, vf, O[dc], 0, 0, 0);
                }
            }
            __builtin_amdgcn_s_setprio(0);

            __syncthreads();  // drains DMA (vmcnt) + all waves done with buf
            cur ^= 1;
        }

        // epilogue: O rows are g*4+r; fetch their lsum via shuffle
        #pragma unroll
        for (int r = 0; r < 4; ++r) {
            const float ls = __shfl(lsum, g * 4 + r);
            const float inv = 1.f / ls;
            const size_t ro =
                (size_t)(b * Tn + qt * 64 + w * 16 + g * 4 + r) * Cn + h * HDn;
            #pragma unroll
            for (int dc = 0; dc < 4; ++dc)
                yb[ro + dc * 16 + l15] = f2b(O[dc][r] * inv);
        }
    }
}

// ---------------------------------------------------------------------------
extern "C" void kernel_launch(void* const* d_in, const int* in_sizes, int n_in,
                              void* d_out, int out_size, void* d_ws, size_t ws_size,
                              hipStream_t stream)
{
    const float* x      = (const float*)d_in[0];
    const float* W_attn = (const float*)d_in[1];
    const float* b_attn = (const float*)d_in[2];
    const float* W_proj = (const float*)d_in[3];
    const float* b_proj = (const float*)d_in[4];
    float* out = (float*)d_out;

    // Workspace (bf16): xb | WaT | WpT | qkvb | yb | vT  (~108 MB)
    u16* xb   = (u16*)d_ws;
    u16* WaT  = xb   + (size_t)Mn * Cn;
    u16* WpT  = WaT  + (size_t)3 * Cn * Cn;
    u16* qkvb = WpT  + (size_t)Cn * Cn;
    u16* yb   = qkvb + (size_t)Mn * 3 * Cn;
    u16* vT   = yb   + (size_t)Mn * Cn;

    cvt_f32_bf16_kernel<<<(Mn * Cn / 4 + 255) / 256, 256, 0, stream>>>(
        (const float4*)x, (ushort4*)xb, Mn * Cn / 4);

    transpose_cvt_kernel<<<dim3(3 * Cn / 32, Cn / 32), 256, 0, stream>>>(
        W_attn, WaT, Cn, 3 * Cn);
    transpose_cvt_kernel<<<dim3(Cn / 32, Cn / 32), 256, 0, stream>>>(
        W_proj, WpT, Cn, Cn);

    // qkv = x @ W_attn + b_attn (bf16 out); flat grid 1536 (24 x 64)
    gemm_bf16_kernel<true><<<24 * 64, 256, 0, stream>>>(
        xb, WaT, b_attn, qkvb, nullptr, 3 * Cn, Cn, 24);

    // vT = per-batch transpose of V section ([T,C] -> [C,T])
    transpose_v_kernel<<<dim3(Cn / 32, Tn / 32, Bn), 256, 0, stream>>>(qkvb, vT);

    // causal MFMA attention -> yb (bf16); flat grid 1024, XCD-grouped
    attn_mfma3_kernel<<<1024, 256, 0, stream>>>(qkvb, vT, yb);

    // out = y @ W_proj + b_proj (f32 out); flat grid 512 (8 x 64)
    gemm_bf16_kernel<false><<<8 * 64, 256, 0, stream>>>(
        yb, WpT, b_proj, nullptr, out, Cn, Cn, 8);
}